// Round 18
// baseline (664.301 us; speedup 1.0000x reference)
//
#include <hip/hip_runtime.h>
#include <stdint.h>

#define NNODES (1024*256)      // 262144
#define NEDGES (2*NNODES)      // 524288
#define H 128
#define LAYERS 4
#define WROW 66                // padded W row in uints (264B) -> breaks 32-bank power-of-2 stride

typedef unsigned int uint;
typedef unsigned short ushort;

typedef short short8 __attribute__((ext_vector_type(8)));
typedef float f32x4 __attribute__((ext_vector_type(4)));
typedef ushort ushort4v __attribute__((ext_vector_type(4)));

__device__ __forceinline__ ushort f2bf(float f){
  uint u = __float_as_uint(f);
  u = (u + 0x7FFFu + ((u>>16)&1u)) >> 16;
  return (ushort)u;
}
__device__ __forceinline__ float bf2f(ushort b){
  return __uint_as_float(((uint)b)<<16);
}

// ---------------- degree precompute ----------------
__global__ void deg_k(const int* __restrict__ ei, int* __restrict__ deg){
  int e = blockIdx.x*256 + threadIdx.x;
  atomicAdd(&deg[ei[NEDGES + e]], 1);   // dst row of edge_index
}

// ---------------- CSR build: exclusive scan of in-degree (+ dis fused) ----------------
__global__ void scan1_k(const int* __restrict__ deg, int* __restrict__ rp, int* __restrict__ bsum,
                        float* __restrict__ dis){
  __shared__ int lds[256];
  int b = blockIdx.x, t = threadIdx.x;
  int base = b*1024 + t*4;
  int4 d = *(const int4*)(deg + base);
  float4 dv;
  dv.x = rsqrtf((float)(d.x+1)); dv.y = rsqrtf((float)(d.y+1));
  dv.z = rsqrtf((float)(d.z+1)); dv.w = rsqrtf((float)(d.w+1));
  *(float4*)(dis + base) = dv;
  int s = d.x + d.y + d.z + d.w;
  lds[t] = s; __syncthreads();
  for (int off=1; off<256; off<<=1){
    int o = (t>=off) ? lds[t-off] : 0;
    __syncthreads();
    lds[t] += o;
    __syncthreads();
  }
  int incl = lds[t];
  int excl = incl - s;
  if (t==255) bsum[b] = incl;
  int p = excl;
  rp[base+0]=p; p+=d.x; rp[base+1]=p; p+=d.y; rp[base+2]=p; p+=d.z; rp[base+3]=p;
}

__global__ void scan2_k(int* __restrict__ bsum){
  __shared__ int lds[256];
  int t = threadIdx.x;
  int s = bsum[t];
  lds[t] = s; __syncthreads();
  for (int off=1; off<256; off<<=1){
    int o = (t>=off) ? lds[t-off] : 0;
    __syncthreads();
    lds[t] += o;
    __syncthreads();
  }
  bsum[t] = lds[t] - s;  // exclusive block offsets
}

__global__ void scan3_k(int* __restrict__ rp, const int* __restrict__ bsum, int* __restrict__ cur){
  int i = blockIdx.x*256 + threadIdx.x;
  int val = rp[i] + bsum[i>>10];
  rp[i] = val;
  cur[i] = val;
  if (i==0) rp[NNODES] = NEDGES;
}

// pack (src, norm-weight) into one int2 per edge
__global__ void fill_k(const int* __restrict__ ei, const float* __restrict__ dis,
                       int* __restrict__ cur, int2* __restrict__ epk){
  int e = blockIdx.x*256 + threadIdx.x;
  int s = ei[e];
  int d = ei[NEDGES + e];
  int pos = atomicAdd(&cur[d], 1);
  int2 pk; pk.x = s; pk.y = __float_as_int(dis[s]*dis[d]);
  epk[pos] = pk;
}

// ---------------- W transpose + bf16 convert: Wt[c][k] = W[k][c] (= W^T row-major) ----------------
__global__ void wconv_k(const float* __restrict__ Ws, ushort* __restrict__ Wt){
  int gid = blockIdx.x*256 + threadIdx.x;     // 4*128*128 = 65536
  int l = gid>>14, rem = gid&16383, c = rem>>7, k = rem&127;
  Wt[(size_t)l*16384 + c*H + k] = f2bf(Ws[(size_t)l*16384 + k*H + c]);
}

// ---------------- node embedding (bf16 h, packed; 8B/thread) ----------------
__global__ void embed_k(const int* __restrict__ x, const float* __restrict__ ce,
                        const float* __restrict__ ne, uint* __restrict__ h){
  int gid = blockIdx.x*256 + threadIdx.x;     // NNODES*32
  int v = gid>>5, q = gid&31;
  int x0 = x[2*v], x1 = x[2*v+1];
  float4 a = *(const float4*)(ce + (size_t)x0*H + q*4);
  float4 b = *(const float4*)(ne + (size_t)x1*H + q*4);
  uint2 o;
  o.x = (uint)f2bf(a.x+b.x) | ((uint)f2bf(a.y+b.y)<<16);
  o.y = (uint)f2bf(a.z+b.z) | ((uint)f2bf(a.w+b.w)<<16);
  *(uint2*)(h + (size_t)v*64 + q*2) = o;
}

__device__ __forceinline__ void acc8(float* a, uint4 m, float w){
  a[0]+=w*bf2f((ushort)m.x); a[1]+=w*bf2f((ushort)(m.x>>16));
  a[2]+=w*bf2f((ushort)m.y); a[3]+=w*bf2f((ushort)(m.y>>16));
  a[4]+=w*bf2f((ushort)m.z); a[5]+=w*bf2f((ushort)(m.z>>16));
  a[6]+=w*bf2f((ushort)m.w); a[7]+=w*bf2f((ushort)(m.w>>16));
}

// ---------------- FUSED layer: gather+norm -> MFMA(W^T) -> bias/ReLU/residual/LN ----------------
// Restructured: (1) W-stage writes issue first but the BARRIER moves to after the tile-0
// gather -- staging latency hides under the gather instead of prefixing it. (2) Each block
// processes 2 node-tiles (128 nodes) off one W-image: halves W L2 traffic; tile 1 needs
// no barrier at all (LDS read-only after tile 0).
__global__ __launch_bounds__(256,4) void layer_k(
    const uint* __restrict__ hin, uint* __restrict__ hout,
    const ushort* __restrict__ Wt,
    const int* __restrict__ rp, const int2* __restrict__ epk,
    const float* __restrict__ dis,
    const float* __restrict__ bias, const float* __restrict__ lng,
    const float* __restrict__ lnb)
{
  __shared__ uint wlds[128*WROW];   // 33792 B

  const int tid = threadIdx.x;
  const int wave = tid>>6, lane = tid&63;
  const int lr = lane&15, lg = lane>>4;

  // stage W^T (8192 uints) into padded LDS rows -- writes only, barrier deferred
  const uint* wt_u = (const uint*)Wt;
#pragma unroll
  for (int i=0;i<32;i++){
    int idx = tid + i*256;
    wlds[(idx>>6)*WROW + (idx&63)] = wt_u[idx];
  }

  for (int t=0; t<2; t++){
    const int node = blockIdx.x*128 + t*64 + wave*16 + lr;

    int beg = rp[node], end = rp[node+1];
    float dv = dis[node];

    // prefetch first 3 edges
    int2 e0, e1, e2;
    if (beg   < end) e0 = epk[beg];
    if (beg+1 < end) e1 = epk[beg+1];
    if (beg+2 < end) e2 = epk[beg+2];

    // residual loads early (D-layout dims ct*16+lg*4); latency hides under gather walk
    ushort4v h4[8];
#pragma unroll
    for (int ct=0; ct<8; ct++)
      h4[ct] = *(const ushort4v*)((const ushort*)hin + (size_t)node*H + ct*16 + lg*4);

    // ---- gather phase: a[kk][i] = agg[node][kk*32+lg*8+i] in fp32 ----
    float a[4][8];
    {
      float sc = dv*dv;
      const uint* hr = hin + (size_t)node*64 + lg*4;
#pragma unroll
      for (int kk=0;kk<4;kk++){
        uint4 m = *(const uint4*)(hr + kk*16);
#pragma unroll
        for (int i=0;i<8;i++) a[kk][i]=0.f;
        acc8(a[kk], m, sc);
      }
    }
    int j = beg;
    for (; j+3 <= end; j += 3){
      int2 c0 = e0, c1 = e1, c2 = e2;
      if (j+3 < end) e0 = epk[j+3];
      if (j+4 < end) e1 = epk[j+4];
      if (j+5 < end) e2 = epk[j+5];
      float w0 = __int_as_float(c0.y), w1 = __int_as_float(c1.y), w2 = __int_as_float(c2.y);
      const uint* r0 = hin + (size_t)c0.x*64 + lg*4;
      const uint* r1 = hin + (size_t)c1.x*64 + lg*4;
      const uint* r2 = hin + (size_t)c2.x*64 + lg*4;
      uint4 m0[4], m1[4], m2[4];
#pragma unroll
      for (int kk=0;kk<4;kk++) m0[kk] = *(const uint4*)(r0 + kk*16);
#pragma unroll
      for (int kk=0;kk<4;kk++) m1[kk] = *(const uint4*)(r1 + kk*16);
#pragma unroll
      for (int kk=0;kk<4;kk++) m2[kk] = *(const uint4*)(r2 + kk*16);
#pragma unroll
      for (int kk=0;kk<4;kk++){ acc8(a[kk], m0[kk], w0); acc8(a[kk], m1[kk], w1); acc8(a[kk], m2[kk], w2); }
    }
    // tail: 0, 1, or 2 edges remain; e0/e1 hold epk[j], epk[j+1]
    if (j < end){
      float w0 = __int_as_float(e0.y);
      const uint* r0 = hin + (size_t)e0.x*64 + lg*4;
#pragma unroll
      for (int kk=0;kk<4;kk++){
        uint4 m0 = *(const uint4*)(r0 + kk*16);
        acc8(a[kk], m0, w0);
      }
    }
    if (j+1 < end){
      float w1 = __int_as_float(e1.y);
      const uint* r1 = hin + (size_t)e1.x*64 + lg*4;
#pragma unroll
      for (int kk=0;kk<4;kk++){
        uint4 m1 = *(const uint4*)(r1 + kk*16);
        acc8(a[kk], m1, w1);
      }
    }

    // ---- convert to B-fragments (in-register) ----
    short8 Bf[4];
#pragma unroll
    for (int kk=0;kk<4;kk++){
      short8 b;
#pragma unroll
      for (int i=0;i<8;i++) b[i] = (short)f2bf(a[kk][i]);
      Bf[kk]=b;
    }

    // barrier only once, AFTER tile-0 gather: W writes are long since complete,
    // so staging latency was hidden under the gather instead of prefixing it.
    if (t==0) __syncthreads();

    // ---- MFMA: hw^T = W^T @ agg^T ; Wf from LDS ----
    f32x4 acc[8];
#pragma unroll
    for (int ct=0; ct<8; ct++){
      f32x4 z = {0.f,0.f,0.f,0.f};
      acc[ct] = z;
#pragma unroll
      for (int kk=0; kk<4; kk++){
        int off = (ct*16+lr)*WROW + kk*16 + lg*4;
        union { uint u[4]; short8 s; } cv;
        uint2 lo = *(const uint2*)&wlds[off];
        uint2 hi = *(const uint2*)&wlds[off+2];
        cv.u[0]=lo.x; cv.u[1]=lo.y; cv.u[2]=hi.x; cv.u[3]=hi.y;
        acc[ct] = __builtin_amdgcn_mfma_f32_16x16x32_bf16(cv.s, Bf[kk], acc[ct], 0, 0, 0);
      }
    }

    // ---- epilogue: z = h + relu(hw + bias); LN over node's 128 dims ----
    float s1 = 0.f, s2 = 0.f;
#pragma unroll
    for (int ct=0; ct<8; ct++){
      float4 b4 = *(const float4*)(bias + ct*16 + lg*4);
#pragma unroll
      for (int i=0; i<4; i++){
        float tv = fmaxf(acc[ct][i] + ((const float*)&b4)[i], 0.f);
        float z = bf2f(h4[ct][i]) + tv;
        acc[ct][i] = z;
        s1 += z; s2 += z*z;
      }
    }
    s1 += __shfl_xor(s1, 16); s2 += __shfl_xor(s2, 16);
    s1 += __shfl_xor(s1, 32); s2 += __shfl_xor(s2, 32);
    float mu  = s1*(1.f/128.f);
    float var = s2*(1.f/128.f) - mu*mu;
    float inv = rsqrtf(var + 1e-5f);

#pragma unroll
    for (int ct=0; ct<8; ct++){
      float4 g4 = *(const float4*)(lng + ct*16 + lg*4);
      float4 c4 = *(const float4*)(lnb + ct*16 + lg*4);
      ushort4v o;
#pragma unroll
      for (int i=0; i<4; i++)
        o[i] = f2bf((acc[ct][i]-mu)*inv*((const float*)&g4)[i] + ((const float*)&c4)[i]);
      *(ushort4v*)((ushort*)hout + (size_t)node*H + ct*16 + lg*4) = o;
    }
  }
}

// ---------------- readout: out[256,32] = h[roots] @ out_w ----------------
__global__ void out_k(const ushort* __restrict__ h, const float* __restrict__ ow, float* __restrict__ out){
  int gid = blockIdx.x*256 + threadIdx.x;    // 8192
  int t = gid>>5, c = gid&31;
  const ushort* hr = h + (size_t)t*1024*H;   // root = node 0 of tree t
  float acc = 0.f;
#pragma unroll 8
  for (int k=0; k<H; k++) acc += bf2f(hr[k])*ow[k*32+c];
  out[gid] = acc;
}

extern "C" void kernel_launch(void* const* d_in, const int* in_sizes, int n_in,
                              void* d_out, int out_size, void* d_ws, size_t ws_size,
                              hipStream_t stream)
{
  const int*   x   = (const int*)d_in[0];
  const int*   ei  = (const int*)d_in[1];
  // d_in[2] = batch (unused; roots are node 0 of each tree)
  const float* ce  = (const float*)d_in[3];
  const float* ne  = (const float*)d_in[4];
  const float* Ws  = (const float*)d_in[5];
  const float* bs  = (const float*)d_in[6];
  const float* lng = (const float*)d_in[7];
  const float* lnb = (const float*)d_in[8];
  const float* ow  = (const float*)d_in[9];
  float* out = (float*)d_out;

  char* p = (char*)d_ws;
  auto alloc = [&](size_t bytes)->char*{ char* r = p; p += (bytes + 255) & ~(size_t)255; return r; };
  uint*   h0   = (uint*)  alloc((size_t)NNODES*64*4);   // bf16 h ping
  uint*   h1   = (uint*)  alloc((size_t)NNODES*64*4);   // bf16 h pong
  ushort* Wt   = (ushort*)alloc((size_t)LAYERS*H*H*2);
  int*    deg  = (int*)   alloc((size_t)NNODES*4);
  float*  dis  = (float*) alloc((size_t)NNODES*4);
  int*    rp   = (int*)   alloc((size_t)(NNODES+1)*4);
  int*    cur  = (int*)   alloc((size_t)NNODES*4);
  int2*   epk  = (int2*)  alloc((size_t)NEDGES*8);
  int*    bsum = (int*)   alloc(256*4);

  hipMemsetAsync(deg, 0, (size_t)NNODES*4, stream);
  deg_k  <<<NEDGES/256, 256, 0, stream>>>(ei, deg);
  scan1_k<<<256, 256, 0, stream>>>(deg, rp, bsum, dis);
  scan2_k<<<1, 256, 0, stream>>>(bsum);
  scan3_k<<<NNODES/256, 256, 0, stream>>>(rp, bsum, cur);
  fill_k <<<NEDGES/256, 256, 0, stream>>>(ei, dis, cur, epk);
  wconv_k<<<256, 256, 0, stream>>>(Ws, Wt);
  embed_k<<<NNODES*32/256, 256, 0, stream>>>(x, ce, ne, h0);

  uint* hin = h0; uint* hout = h1;
  for (int l=0; l<LAYERS; l++){
    layer_k<<<NNODES/128, 256, 0, stream>>>(hin, hout, Wt + (size_t)l*H*H,
                                            rp, epk, dis,
                                            bs + (size_t)l*H, lng + (size_t)l*H, lnb + (size_t)l*H);
    uint* tmp = hin; hin = hout; hout = tmp;
  }
  // after 4 swaps, final result is back in h0 (= hin)
  out_k<<<32, 256, 0, stream>>>((const ushort*)hin, ow, out);
}

// Round 20
// 392.552 us; speedup vs baseline: 1.6923x; 1.6923x over previous
//
#include <hip/hip_runtime.h>
#include <stdint.h>

#define NNODES (1024*256)      // 262144
#define NEDGES (2*NNODES)      // 524288
#define H 128
#define LAYERS 4
#define WROW 66                // padded W row in uints (264B) -> breaks 32-bank power-of-2 stride

typedef unsigned int uint;
typedef unsigned short ushort;

typedef short short8 __attribute__((ext_vector_type(8)));
typedef float f32x4 __attribute__((ext_vector_type(4)));
typedef ushort ushort4v __attribute__((ext_vector_type(4)));

__device__ __forceinline__ ushort f2bf(float f){
  uint u = __float_as_uint(f);
  u = (u + 0x7FFFu + ((u>>16)&1u)) >> 16;
  return (ushort)u;
}
__device__ __forceinline__ float bf2f(ushort b){
  return __uint_as_float(((uint)b)<<16);
}

// ---------------- degree precompute ----------------
__global__ void deg_k(const int* __restrict__ ei, int* __restrict__ deg){
  int e = blockIdx.x*256 + threadIdx.x;
  atomicAdd(&deg[ei[NEDGES + e]], 1);   // dst row of edge_index
}

// ---------------- CSR build: exclusive scan of in-degree (+ dis fused) ----------------
__global__ void scan1_k(const int* __restrict__ deg, int* __restrict__ rp, int* __restrict__ bsum,
                        float* __restrict__ dis){
  __shared__ int lds[256];
  int b = blockIdx.x, t = threadIdx.x;
  int base = b*1024 + t*4;
  int4 d = *(const int4*)(deg + base);
  // fused dis: rsqrt(deg+1), always > 0
  float4 dv;
  dv.x = rsqrtf((float)(d.x+1)); dv.y = rsqrtf((float)(d.y+1));
  dv.z = rsqrtf((float)(d.z+1)); dv.w = rsqrtf((float)(d.w+1));
  *(float4*)(dis + base) = dv;
  int s = d.x + d.y + d.z + d.w;
  lds[t] = s; __syncthreads();
  for (int off=1; off<256; off<<=1){
    int o = (t>=off) ? lds[t-off] : 0;
    __syncthreads();
    lds[t] += o;
    __syncthreads();
  }
  int incl = lds[t];
  int excl = incl - s;
  if (t==255) bsum[b] = incl;
  int p = excl;
  rp[base+0]=p; p+=d.x; rp[base+1]=p; p+=d.y; rp[base+2]=p; p+=d.z; rp[base+3]=p;
}

__global__ void scan2_k(int* __restrict__ bsum){
  __shared__ int lds[256];
  int t = threadIdx.x;
  int s = bsum[t];
  lds[t] = s; __syncthreads();
  for (int off=1; off<256; off<<=1){
    int o = (t>=off) ? lds[t-off] : 0;
    __syncthreads();
    lds[t] += o;
    __syncthreads();
  }
  bsum[t] = lds[t] - s;  // exclusive block offsets
}

__global__ void scan3_k(int* __restrict__ rp, const int* __restrict__ bsum, int* __restrict__ cur){
  int i = blockIdx.x*256 + threadIdx.x;
  int val = rp[i] + bsum[i>>10];
  rp[i] = val;
  cur[i] = val;
  if (i==0) rp[NNODES] = NEDGES;
}

// pack (src, norm-weight) into one int2 per edge
__global__ void fill_k(const int* __restrict__ ei, const float* __restrict__ dis,
                       int* __restrict__ cur, int2* __restrict__ epk){
  int e = blockIdx.x*256 + threadIdx.x;
  int s = ei[e];
  int d = ei[NEDGES + e];
  int pos = atomicAdd(&cur[d], 1);
  int2 pk; pk.x = s; pk.y = __float_as_int(dis[s]*dis[d]);
  epk[pos] = pk;
}

// ---------------- W transpose + bf16 convert: Wt[c][k] = W[k][c] (= W^T row-major) ----------------
__global__ void wconv_k(const float* __restrict__ Ws, ushort* __restrict__ Wt){
  int gid = blockIdx.x*256 + threadIdx.x;     // 4*128*128 = 65536
  int l = gid>>14, rem = gid&16383, c = rem>>7, k = rem&127;
  Wt[(size_t)l*16384 + c*H + k] = f2bf(Ws[(size_t)l*16384 + k*H + c]);
}

// ---------------- node embedding (bf16 h, packed; 8B/thread) ----------------
__global__ void embed_k(const int* __restrict__ x, const float* __restrict__ ce,
                        const float* __restrict__ ne, uint* __restrict__ h){
  int gid = blockIdx.x*256 + threadIdx.x;     // NNODES*32
  int v = gid>>5, q = gid&31;
  int x0 = x[2*v], x1 = x[2*v+1];
  float4 a = *(const float4*)(ce + (size_t)x0*H + q*4);
  float4 b = *(const float4*)(ne + (size_t)x1*H + q*4);
  uint2 o;
  o.x = (uint)f2bf(a.x+b.x) | ((uint)f2bf(a.y+b.y)<<16);
  o.y = (uint)f2bf(a.z+b.z) | ((uint)f2bf(a.w+b.w)<<16);
  *(uint2*)(h + (size_t)v*64 + q*2) = o;
}

__device__ __forceinline__ void acc8(float* a, uint4 m, float w){
  a[0]+=w*bf2f((ushort)m.x); a[1]+=w*bf2f((ushort)(m.x>>16));
  a[2]+=w*bf2f((ushort)m.y); a[3]+=w*bf2f((ushort)(m.y>>16));
  a[4]+=w*bf2f((ushort)m.z); a[5]+=w*bf2f((ushort)(m.z>>16));
  a[6]+=w*bf2f((ushort)m.w); a[7]+=w*bf2f((ushort)(m.w>>16));
}

// ---------------- FUSED layer: gather+norm -> MFMA(W^T) -> bias/ReLU/residual/LN ----------------
// Best-measured config (round 16, 394.3 us): 512-thread blocks at (512,4), one 33.8KB W-image
// serves 8 waves; body compiles to 64 VGPR (no spill). Gather is at its random-access floor:
// unroll depth (r15), 2x wave capacity (r16), degree uniformity (r17) all null; ~2.2 TB/s
// on uniform-random 256B-row gathers = pattern-specific memory floor.
__global__ __launch_bounds__(512,4) void layer_k(
    const uint* __restrict__ hin, uint* __restrict__ hout,
    const ushort* __restrict__ Wt,
    const int* __restrict__ rp, const int2* __restrict__ epk,
    const float* __restrict__ dis,
    const float* __restrict__ bias, const float* __restrict__ lng,
    const float* __restrict__ lnb)
{
  __shared__ uint wlds[128*WROW];   // 33792 B

  const int tid = threadIdx.x;
  const int wave = tid>>6, lane = tid&63;
  const int lr = lane&15, lg = lane>>4;
  const int node = blockIdx.x*128 + wave*16 + lr;   // 8 waves x 16 nodes = 128 nodes/block

  // per-node metadata early; W staging hides the latency
  int beg = rp[node], end = rp[node+1];
  float dv = dis[node];

  // stage W^T (8192 uints) into padded LDS rows (512 threads -> 16 iters)
  const uint* wt_u = (const uint*)Wt;
#pragma unroll
  for (int i=0;i<16;i++){
    int idx = tid + i*512;
    wlds[(idx>>6)*WROW + (idx&63)] = wt_u[idx];
  }
  __syncthreads();

  // prefetch first 3 edges
  int2 e0, e1, e2;
  if (beg   < end) e0 = epk[beg];
  if (beg+1 < end) e1 = epk[beg+1];
  if (beg+2 < end) e2 = epk[beg+2];

  // residual loads early (D-layout dims ct*16+lg*4); latency hides under gather walk
  ushort4v h4[8];
#pragma unroll
  for (int ct=0; ct<8; ct++)
    h4[ct] = *(const ushort4v*)((const ushort*)hin + (size_t)node*H + ct*16 + lg*4);

  // ---- gather phase: a[kk][i] = agg[node][kk*32+lg*8+i] in fp32 ----
  float a[4][8];
  {
    float sc = dv*dv;
    const uint* hr = hin + (size_t)node*64 + lg*4;
#pragma unroll
    for (int kk=0;kk<4;kk++){
      uint4 m = *(const uint4*)(hr + kk*16);
#pragma unroll
      for (int i=0;i<8;i++) a[kk][i]=0.f;
      acc8(a[kk], m, sc);
    }
  }
  int j = beg;
  for (; j+3 <= end; j += 3){
    int2 c0 = e0, c1 = e1, c2 = e2;
    if (j+3 < end) e0 = epk[j+3];
    if (j+4 < end) e1 = epk[j+4];
    if (j+5 < end) e2 = epk[j+5];
    float w0 = __int_as_float(c0.y), w1 = __int_as_float(c1.y), w2 = __int_as_float(c2.y);
    const uint* r0 = hin + (size_t)c0.x*64 + lg*4;
    const uint* r1 = hin + (size_t)c1.x*64 + lg*4;
    const uint* r2 = hin + (size_t)c2.x*64 + lg*4;
    uint4 m0[4], m1[4], m2[4];
#pragma unroll
    for (int kk=0;kk<4;kk++) m0[kk] = *(const uint4*)(r0 + kk*16);
#pragma unroll
    for (int kk=0;kk<4;kk++) m1[kk] = *(const uint4*)(r1 + kk*16);
#pragma unroll
    for (int kk=0;kk<4;kk++) m2[kk] = *(const uint4*)(r2 + kk*16);
#pragma unroll
    for (int kk=0;kk<4;kk++){ acc8(a[kk], m0[kk], w0); acc8(a[kk], m1[kk], w1); acc8(a[kk], m2[kk], w2); }
  }
  // tail: 0, 1, or 2 edges remain; e0/e1 hold epk[j], epk[j+1]
  if (j < end){
    float w0 = __int_as_float(e0.y);
    const uint* r0 = hin + (size_t)e0.x*64 + lg*4;
#pragma unroll
    for (int kk=0;kk<4;kk++){
      uint4 m0 = *(const uint4*)(r0 + kk*16);
      acc8(a[kk], m0, w0);
    }
  }
  if (j+1 < end){
    float w1 = __int_as_float(e1.y);
    const uint* r1 = hin + (size_t)e1.x*64 + lg*4;
#pragma unroll
    for (int kk=0;kk<4;kk++){
      uint4 m1 = *(const uint4*)(r1 + kk*16);
      acc8(a[kk], m1, w1);
    }
  }

  // ---- convert to B-fragments (in-register) ----
  short8 Bf[4];
#pragma unroll
  for (int kk=0;kk<4;kk++){
    short8 b;
#pragma unroll
    for (int i=0;i<8;i++) b[i] = (short)f2bf(a[kk][i]);
    Bf[kk]=b;
  }

  // ---- MFMA: hw^T = W^T @ agg^T ; Wf from LDS ----
  f32x4 acc[8];
#pragma unroll
  for (int ct=0; ct<8; ct++){
    f32x4 z = {0.f,0.f,0.f,0.f};
    acc[ct] = z;
#pragma unroll
    for (int kk=0; kk<4; kk++){
      int off = (ct*16+lr)*WROW + kk*16 + lg*4;
      union { uint u[4]; short8 s; } cv;
      uint2 lo = *(const uint2*)&wlds[off];
      uint2 hi = *(const uint2*)&wlds[off+2];
      cv.u[0]=lo.x; cv.u[1]=lo.y; cv.u[2]=hi.x; cv.u[3]=hi.y;
      acc[ct] = __builtin_amdgcn_mfma_f32_16x16x32_bf16(cv.s, Bf[kk], acc[ct], 0, 0, 0);
    }
  }

  // ---- epilogue: z = h + relu(hw + bias); LN over node's 128 dims ----
  float s1 = 0.f, s2 = 0.f;
#pragma unroll
  for (int ct=0; ct<8; ct++){
    float4 b4 = *(const float4*)(bias + ct*16 + lg*4);
#pragma unroll
    for (int i=0; i<4; i++){
      float tv = fmaxf(acc[ct][i] + ((const float*)&b4)[i], 0.f);
      float z = bf2f(h4[ct][i]) + tv;
      acc[ct][i] = z;
      s1 += z; s2 += z*z;
    }
  }
  s1 += __shfl_xor(s1, 16); s2 += __shfl_xor(s2, 16);
  s1 += __shfl_xor(s1, 32); s2 += __shfl_xor(s2, 32);
  float mu  = s1*(1.f/128.f);
  float var = s2*(1.f/128.f) - mu*mu;
  float inv = rsqrtf(var + 1e-5f);

#pragma unroll
  for (int ct=0; ct<8; ct++){
    float4 g4 = *(const float4*)(lng + ct*16 + lg*4);
    float4 c4 = *(const float4*)(lnb + ct*16 + lg*4);
    ushort4v o;
#pragma unroll
    for (int i=0; i<4; i++)
      o[i] = f2bf((acc[ct][i]-mu)*inv*((const float*)&g4)[i] + ((const float*)&c4)[i]);
    *(ushort4v*)((ushort*)hout + (size_t)node*H + ct*16 + lg*4) = o;
  }
}

// ---------------- readout: out[256,32] = h[roots] @ out_w ----------------
__global__ void out_k(const ushort* __restrict__ h, const float* __restrict__ ow, float* __restrict__ out){
  int gid = blockIdx.x*256 + threadIdx.x;    // 8192
  int t = gid>>5, c = gid&31;
  const ushort* hr = h + (size_t)t*1024*H;   // root = node 0 of tree t
  float acc = 0.f;
#pragma unroll 8
  for (int k=0; k<H; k++) acc += bf2f(hr[k])*ow[k*32+c];
  out[gid] = acc;
}

extern "C" void kernel_launch(void* const* d_in, const int* in_sizes, int n_in,
                              void* d_out, int out_size, void* d_ws, size_t ws_size,
                              hipStream_t stream)
{
  const int*   x   = (const int*)d_in[0];
  const int*   ei  = (const int*)d_in[1];
  // d_in[2] = batch (unused; roots are node 0 of each tree)
  const float* ce  = (const float*)d_in[3];
  const float* ne  = (const float*)d_in[4];
  const float* Ws  = (const float*)d_in[5];
  const float* bs  = (const float*)d_in[6];
  const float* lng = (const float*)d_in[7];
  const float* lnb = (const float*)d_in[8];
  const float* ow  = (const float*)d_in[9];
  float* out = (float*)d_out;

  char* p = (char*)d_ws;
  auto alloc = [&](size_t bytes)->char*{ char* r = p; p += (bytes + 255) & ~(size_t)255; return r; };
  uint*   h0   = (uint*)  alloc((size_t)NNODES*64*4);   // bf16 h ping
  uint*   h1   = (uint*)  alloc((size_t)NNODES*64*4);   // bf16 h pong
  ushort* Wt   = (ushort*)alloc((size_t)LAYERS*H*H*2);
  int*    deg  = (int*)   alloc((size_t)NNODES*4);
  float*  dis  = (float*) alloc((size_t)NNODES*4);
  int*    rp   = (int*)   alloc((size_t)(NNODES+1)*4);
  int*    cur  = (int*)   alloc((size_t)NNODES*4);
  int2*   epk  = (int2*)  alloc((size_t)NEDGES*8);
  int*    bsum = (int*)   alloc(256*4);

  hipMemsetAsync(deg, 0, (size_t)NNODES*4, stream);
  deg_k  <<<NEDGES/256, 256, 0, stream>>>(ei, deg);
  scan1_k<<<256, 256, 0, stream>>>(deg, rp, bsum, dis);
  scan2_k<<<1, 256, 0, stream>>>(bsum);
  scan3_k<<<NNODES/256, 256, 0, stream>>>(rp, bsum, cur);
  fill_k <<<NEDGES/256, 256, 0, stream>>>(ei, dis, cur, epk);
  wconv_k<<<256, 256, 0, stream>>>(Ws, Wt);
  embed_k<<<NNODES*32/256, 256, 0, stream>>>(x, ce, ne, h0);

  uint* hin = h0; uint* hout = h1;
  for (int l=0; l<LAYERS; l++){
    layer_k<<<NNODES/128, 512, 0, stream>>>(hin, hout, Wt + (size_t)l*H*H,
                                            rp, epk, dis,
                                            bs + (size_t)l*H, lng + (size_t)l*H, lnb + (size_t)l*H);
    uint* tmp = hin; hin = hout; hout = tmp;
  }
  // after 4 swaps, final result is back in h0 (= hin)
  out_k<<<32, 256, 0, stream>>>((const ushort*)hin, ow, out);
}